// Round 7
// baseline (709.389 us; speedup 1.0000x reference)
//
#include <hip/hip_runtime.h>
#include <math.h>

// Problem constants
#define DIM 64
#define KCB 512
#define NWIN 524288              // 16384 * 32 windows
#define ZQN (NWIN * DIM)         // 33554432
#define WPB 256                  // windows per block (256 threads, 4 waves)
#define NBLK (NWIN / WPB)        // 2048 blocks -> ~4 resident/CU, 8/CU lifetime

typedef __attribute__((ext_vector_type(8))) short bf16x8;  // 8 bf16 = 4 VGPRs
typedef __attribute__((ext_vector_type(4))) float f32x4;

__device__ __forceinline__ unsigned bfbits(float f) { return __float_as_uint(f) >> 16; }

// pack 8 fp32 -> 8 bf16 (truncation; tolerance budget is enormous)
__device__ __forceinline__ int4 pack8(float4 a, float4 b) {
    int4 r;
    r.x = (int)(bfbits(a.x) | (__float_as_uint(a.y) & 0xffff0000u));
    r.y = (int)(bfbits(a.z) | (__float_as_uint(a.w) & 0xffff0000u));
    r.z = (int)(bfbits(b.x) | (__float_as_uint(b.y) & 0xffff0000u));
    r.w = (int)(bfbits(b.z) | (__float_as_uint(b.w) & 0xffff0000u));
    return r;
}

// ---------------------------------------------------------------------------
// Preformat: build the codebook MFMA B-fragments (64 KiB) + halved row norms
// (2 KiB) ONCE, in workspace. Every scan block previously rebuilt this into
// LDS (64 KB/block + block-wide barrier) -- the L2-resident 66 KB needs no
// staging at all (guide common-mistake #7).
// ---------------------------------------------------------------------------
__global__ __launch_bounds__(512) void vq_preformat_kernel(
    const float* __restrict__ cb, int4* __restrict__ bfg, float* __restrict__ nrm)
{
    const int t = threadIdx.x;   // 0..511
    const float4* c4 = (const float4*)cb;
    float s = 0.f;
#pragma unroll
    for (int i = 0; i < 16; ++i) {
        float4 v = c4[t * 16 + i];
        s += v.x * v.x + v.y * v.y + v.z * v.z + v.w * v.w;
    }
    nrm[t] = 0.5f * s;
#pragma unroll
    for (int i = 0; i < 8; ++i) {
        int f = i * 512 + t;
        int L = f & 63, rest = f >> 6, h = rest & 1, c = rest >> 1;  // c=0..31
        int n = c * 16 + (L & 15);
        int k = h * 32 + (L >> 4) * 8;
        const float4* s4 = (const float4*)(cb + n * DIM + k);
        bfg[(c * 2 + h) * 64 + L] = pack8(s4[0], s4[1]);
    }
}

// ---------------------------------------------------------------------------
// v10: barrier-free streaming scan+gather.
//  Post-mortems v3..v9: every structure with per-block LDS B-staging +
//  barrier lands at 80-110 us (phase-lockstep serializes HBM vs MFMA;
//  occupancy/VGPR/fusion changes were all ~neutral). v10 removes the cause:
//   - B-frags + norms read from GLOBAL workspace (L2-hot 66 KB, one-pair
//     register lookahead in the scan loop). No 64 KB LDS, no staging phase.
//   - ZERO __syncthreads: idx goes through wave-private LDS (ds_write ->
//     lgkmcnt -> ds_read within the same wave), histogram = direct global
//     atomics (524K total), loss = wave shfl-reduce + one atomic per wave.
//   - 2048 small blocks (256 thr / 256 windows) free-run at ~4 blocks/CU:
//     different blocks sit in different phases, overlapping read bursts,
//     MFMA scans and write bursts per CU.
//   - zq gathered as exact fp32 from global cb (L2-resident), coalesced
//     1 KB/wave stores.
//  score = 0.5||c||^2 - <z,c> entirely in MFMA (A = -z bf16, C = norms);
//  argmin: idx packed into low 9 mantissa bits + v_min3_f32.
// MFMA 16x16x32 bf16: A[m=lane&15][k=quad*8+j], B[k][n=lane&15],
// D: col(n)=lane&15, row(m)=quad*4+reg.
// ---------------------------------------------------------------------------
__global__ __launch_bounds__(256, 4) void vq_scan_kernel(
    const float* __restrict__ ze, const float* __restrict__ cb,
    const int4* __restrict__ bfg, const float* __restrict__ nrm,
    float* __restrict__ out_idx, float* __restrict__ zq,
    int* __restrict__ counts, float* __restrict__ lossAcc)
{
    __shared__ int idx_s[WPB];      // 1 KiB, wave-private 64-entry regions

    const int t    = threadIdx.x;   // 0..255
    const int lane = t & 63;
    const int wv   = t >> 6;        // wave 0..3
    const int q    = lane >> 4;
    const int l15  = lane & 15;
    const long blk = blockIdx.x;
    const long wbase = blk * (long)WPB + wv * 64;   // this wave's first window

    // ---- A-tile loads (wave-private, no staging dependency)
    float4 ldv[16];
    {
        const float4* z4 = (const float4*)ze + wbase * 16;
#pragma unroll
        for (int tt = 0; tt < 4; ++tt)
#pragma unroll
            for (int h = 0; h < 2; ++h)
#pragma unroll
                for (int i = 0; i < 2; ++i)
                    ldv[tt * 4 + h * 2 + i] = z4[(tt * 16 + l15) * 16 + h * 8 + q * 2 + i];
    }

    // ---- pack A to NEGATED bf16 frags + window norms
    bf16x8 afrag[4][2];
    float  znorm[4];
#pragma unroll
    for (int tt = 0; tt < 4; ++tt) {
        float part = 0.f;
#pragma unroll
        for (int h = 0; h < 2; ++h) {
            float4 a0 = ldv[tt * 4 + h * 2], a1 = ldv[tt * 4 + h * 2 + 1];
            part += a0.x*a0.x + a0.y*a0.y + a0.z*a0.z + a0.w*a0.w
                  + a1.x*a1.x + a1.y*a1.y + a1.z*a1.z + a1.w*a1.w;
            int4 p = pack8(a0, a1);
            p.x ^= 0x80008000; p.y ^= 0x80008000;   // negate both bf16 halves
            p.z ^= 0x80008000; p.w ^= 0x80008000;
            afrag[tt][h] = __builtin_bit_cast(bf16x8, p);
        }
        part += __shfl_xor(part, 16, 64);
        part += __shfl_xor(part, 32, 64);
        znorm[tt] = part;
    }

    float best[4][4];
#pragma unroll
    for (int tt = 0; tt < 4; ++tt)
#pragma unroll
        for (int r = 0; r < 4; ++r) best[tt][r] = __uint_as_float(0x7e000000u);

    // ---- MFMA scan over 512 codes; B-frags from global (L2-hot) with a
    // one-chunk-pair register lookahead.
    bf16x8 pb0 = __builtin_bit_cast(bf16x8, bfg[0 * 64 + lane]);
    bf16x8 pb1 = __builtin_bit_cast(bf16x8, bfg[1 * 64 + lane]);
    bf16x8 pb2 = __builtin_bit_cast(bf16x8, bfg[2 * 64 + lane]);
    bf16x8 pb3 = __builtin_bit_cast(bf16x8, bfg[3 * 64 + lane]);
    float  pn0 = nrm[l15];
    float  pn1 = nrm[16 + l15];

    for (int cp = 0; cp < 16; ++cp) {
        f32x4 e0[4], e1[4];
        {
            f32x4 nrm4 = {pn0, pn0, pn0, pn0};
#pragma unroll
            for (int tt = 0; tt < 4; ++tt) {
                e0[tt] = __builtin_amdgcn_mfma_f32_16x16x32_bf16(afrag[tt][0], pb0, nrm4, 0, 0, 0);
                e0[tt] = __builtin_amdgcn_mfma_f32_16x16x32_bf16(afrag[tt][1], pb1, e0[tt], 0, 0, 0);
            }
        }
        {
            f32x4 nrm4 = {pn1, pn1, pn1, pn1};
#pragma unroll
            for (int tt = 0; tt < 4; ++tt) {
                e1[tt] = __builtin_amdgcn_mfma_f32_16x16x32_bf16(afrag[tt][0], pb2, nrm4, 0, 0, 0);
                e1[tt] = __builtin_amdgcn_mfma_f32_16x16x32_bf16(afrag[tt][1], pb3, e1[tt], 0, 0, 0);
            }
        }
        if (cp < 15) {   // prefetch next chunk pair (drains under epilogue+MFMA)
            pb0 = __builtin_bit_cast(bf16x8, bfg[(4 * cp + 4) * 64 + lane]);
            pb1 = __builtin_bit_cast(bf16x8, bfg[(4 * cp + 5) * 64 + lane]);
            pb2 = __builtin_bit_cast(bf16x8, bfg[(4 * cp + 6) * 64 + lane]);
            pb3 = __builtin_bit_cast(bf16x8, bfg[(4 * cp + 7) * 64 + lane]);
            pn0 = nrm[(cp + 1) * 32 + l15];
            pn1 = nrm[(cp + 1) * 32 + 16 + l15];
        }
        const unsigned n0 = (unsigned)cp * 32 + (unsigned)l15;
        const unsigned n1 = n0 + 16;
#pragma unroll
        for (int tt = 0; tt < 4; ++tt)
#pragma unroll
            for (int r = 0; r < 4; ++r) {
                float p0 = __uint_as_float((__float_as_uint(e0[tt][r]) & ~511u) | n0);
                float p1 = __uint_as_float((__float_as_uint(e1[tt][r]) & ~511u) | n1);
                best[tt][r] = fminf(fminf(best[tt][r], p0), p1);   // -> v_min3_f32
            }
    }

    // ---- min across the 16 lanes of each quad (n-direction)
#pragma unroll
    for (int tt = 0; tt < 4; ++tt)
#pragma unroll
        for (int r = 0; r < 4; ++r) {
            float v = best[tt][r];
            v = fminf(v, __shfl_xor(v, 1, 64));
            v = fminf(v, __shfl_xor(v, 2, 64));
            v = fminf(v, __shfl_xor(v, 4, 64));
            v = fminf(v, __shfl_xor(v, 8, 64));
            best[tt][r] = v;
        }

    // ---- owner lanes (l15 == q*4+r): idx -> wave-private LDS, loss, hist.
    // r is compile-time (rule #20). Direct global atomics for the histogram
    // (64/wave; cheaper than an LDS hist + 512-wide flush at this block size).
    float lsum = 0.f;
#pragma unroll
    for (int r = 0; r < 4; ++r) {
        if (l15 == q * 4 + r) {
#pragma unroll
            for (int tt = 0; tt < 4; ++tt) {
                unsigned bb = __float_as_uint(best[tt][r]);
                int   n  = (int)(bb & 511u);
                float sc = __uint_as_float(bb & ~511u);
                lsum += fmaf(2.f, sc, znorm[tt]);      // d^2 = ||z||^2 + 2*score
                idx_s[wv * 64 + tt * 16 + l15] = n;
                atomicAdd(&counts[n], 1);
            }
        }
    }
    // same-wave ds_write -> ds_read: lanes run in lockstep, only the LDS
    // counter must drain (no barrier; consumers below are memory ops).
    asm volatile("s_waitcnt lgkmcnt(0)" ::: "memory");

    // ---- coalesced idx write (one float per lane, 256 B per wave)
    out_idx[wbase + lane] = (float)idx_s[wv * 64 + lane];

    // ---- zq gather from GLOBAL cb (L2-resident, exact fp32), coalesced
    // 1 KiB contiguous store per wave-iteration.
    {
        const f32x4* c4g = (const f32x4*)cb;
        f32x4*       zq4 = (f32x4*)zq;
        const long zb = wbase * 16;   // float4 units
#pragma unroll
        for (int it = 0; it < 16; ++it) {
            int w_loc = it * 4 + (lane >> 4);
            int n = idx_s[wv * 64 + w_loc];
            f32x4 o = c4g[n * 16 + l15];
            zq4[zb + (long)w_loc * 16 + l15] = o;
        }
    }

    // ---- loss: wave reduce + one atomic per wave
#pragma unroll
    for (int off = 32; off; off >>= 1) lsum += __shfl_down(lsum, off, 64);
    if (lane == 0) atomicAdd(lossAcc, lsum);
}

// ---------------------------------------------------------------------------
// Finalize: entropy from counts + loss scalars
// ---------------------------------------------------------------------------
__global__ __launch_bounds__(512) void vq_finalize_kernel(
    const int* __restrict__ counts, const float* __restrict__ lossAcc,
    float* __restrict__ outs)
{
    __shared__ float partial[8];
    const int t = threadIdx.x;

    float p = (float)counts[t] * 0.1f;
    float term = p * logf(p + 1e-10f);
#pragma unroll
    for (int off = 32; off; off >>= 1) term += __shfl_down(term, off, 64);
    if ((t & 63) == 0) partial[t >> 6] = term;
    __syncthreads();
    if (t == 0) {
        float e = 0.f;
#pragma unroll
        for (int i = 0; i < 8; ++i) e += partial[i];
        float loss = lossAcc[0] / (float)ZQN;
        outs[0] = loss;
        outs[1] = loss;
        outs[2] = e;
    }
}

extern "C" void kernel_launch(void* const* d_in, const int* in_sizes, int n_in,
                              void* d_out, int out_size, void* d_ws, size_t ws_size,
                              hipStream_t stream) {
    const float* ze = (const float*)d_in[0];   // [16384, 2048] fp32
    const float* cb = (const float*)d_in[1];   // [512, 64] fp32
    float* out = (float*)d_out;

    // d_out layout: [idx: NWIN | zq: ZQN | vq_e | vq_commit | entropy]
    float* out_idx = out;
    float* out_zq  = out + NWIN;
    float* out_scl = out + NWIN + (long)ZQN;

    // workspace layout: [counts 2KB | lossAcc | pad | bfg 64KB | nrm 2KB]
    int*   counts  = (int*)d_ws;
    float* lossAcc = (float*)((char*)d_ws + KCB * sizeof(int));
    int4*  bfg     = (int4*)((char*)d_ws + 4096);
    float* nrm     = (float*)((char*)d_ws + 4096 + 65536);
    hipMemsetAsync(d_ws, 0, KCB * sizeof(int) + sizeof(float), stream);

    vq_preformat_kernel<<<1, 512, 0, stream>>>(cb, bfg, nrm);
    vq_scan_kernel<<<NBLK, 256, 0, stream>>>(ze, cb, bfg, nrm,
                                             out_idx, out_zq, counts, lossAcc);
    vq_finalize_kernel<<<1, KCB, 0, stream>>>(counts, lossAcc, out_scl);
}